// Round 5
// baseline (137.315 us; speedup 1.0000x reference)
//
#include <hip/hip_runtime.h>
#include <math.h>

#define KS   5
#define K2   25
#define DYN  32
#define CTOT 64
#define BB   4
#define HH   256
#define WW   256
#define PLANE (HH * WW)
#define LROW 264                 // floats/LDS row; %4==0 (b128 align), %32==8 (bank stagger)
#define NROW 7                   // 6 data rows + 1 dump row for OOB staging
#define NTHR 128

// Block = 2 output rows x 64 threads x 4 px. Grid (H/2, B) = 512 -> 2 blocks/CU.
// Unified 64-stage pipeline over channels (score: 32..63, output: 0..31),
// double-buffered LDS tile (6 rows + zeroed halo => implicit zero padding),
// depth-2 register prefetch (two float4x3 sets, written to LDS 2 stages after
// issue -> vmcnt wait lands ~1000+ cyc after load issue).
// LDS reads are ds_read_b128: halo offset 2 puts col (w0-2) at 16B-aligned
// index w0; 2 reads/row x 5 rows per channel, conflict-free.
__global__ __launch_bounds__(NTHR, 1)
void local_attn_kernel(const float* __restrict__ x,
                       const float* __restrict__ kern,
                       float* __restrict__ out)
{
    __shared__ __align__(16) float lds[2][NROW][LROW];
    __shared__ float kw[K2];

    const int tid = threadIdx.x;
    for (int i = tid; i < 2 * NROW * LROW; i += NTHR) ((float*)lds)[i] = 0.0f;
    if (tid < K2) kw[tid] = kern[tid] * (1.0f / KS);

    const int tx = tid & 63;
    const int ty = tid >> 6;        // wave index == output row within block
    const int w0 = tx << 2;
    const int h0 = blockIdx.x * 2;
    const int h  = h0 + ty;
    const int b  = blockIdx.y;

    const float* xb = x + (size_t)b * CTOT * PLANE;
    float*       ob = out + (size_t)b * DYN * PLANE + h * WW + w0;

    // staging map: q = tid + k*128 -> tile row q>>6 (0..5), quad-col q&63
    int goff[3], loff[3];
#pragma unroll
    for (int k = 0; k < 3; ++k) {
        const int q   = tid + k * NTHR;
        const int row = q >> 6;
        const int col = (q & 63) << 2;
        const int r   = h0 - 2 + row;
        const bool v  = (unsigned)r < (unsigned)HH;
        goff[k] = min(max(r, 0), HH - 1) * WW + col;
        loff[k] = (v ? row : 6) * LROW + 2 + col;   // OOB rows -> dump row 6
    }

    float s[4][K2];
#pragma unroll
    for (int p = 0; p < 4; ++p)
#pragma unroll
        for (int k = 0; k < K2; ++k) s[p][k] = 0.0f;

    float* buf0 = (float*)lds;
    float* buf1 = (float*)lds + NROW * LROW;

    auto loadset = [&](int ch, float4& q0, float4& q1, float4& q2) {
        const float* xc = xb + ch * PLANE;
        q0 = *(const float4*)(xc + goff[0]);
        q1 = *(const float4*)(xc + goff[1]);
        q2 = *(const float4*)(xc + goff[2]);
    };
    auto writeset = [&](float* lb, const float4& q0, const float4& q1, const float4& q2) {
        *(float2*)(lb + loff[0])     = make_float2(q0.x, q0.y);
        *(float2*)(lb + loff[0] + 2) = make_float2(q0.z, q0.w);
        *(float2*)(lb + loff[1])     = make_float2(q1.x, q1.y);
        *(float2*)(lb + loff[1] + 2) = make_float2(q1.z, q1.w);
        *(float2*)(lb + loff[2])     = make_float2(q2.x, q2.y);
        *(float2*)(lb + loff[2] + 2) = make_float2(q2.z, q2.w);
    };
    // stage t -> channel: score phase t<32 -> 32+t; output phase -> t-32
    auto CH = [](int t) { return t < 32 ? 32 + t : t - 32; };

    auto compute = [&](int t, const float* bufbase) {
        const float* base = bufbase + ty * LROW;
        if (t < 32) {
            float ctr[4];
            {   // center row first (i == 2): holds the 4 center pixels
                const float* rp = base + 2 * LROW + w0;
                float4 a = *(const float4*)(rp);
                float4 c = *(const float4*)(rp + 4);
                float f[8] = {a.x, a.y, a.z, a.w, c.x, c.y, c.z, c.w};
                ctr[0] = f[2]; ctr[1] = f[3]; ctr[2] = f[4]; ctr[3] = f[5];
#pragma unroll
                for (int j = 0; j < KS; ++j)
#pragma unroll
                    for (int p = 0; p < 4; ++p)
                        s[p][2 * KS + j] = fmaf(f[p + j], ctr[p], s[p][2 * KS + j]);
            }
#pragma unroll
            for (int i = 0; i < KS; ++i) {
                if (i == 2) continue;
                const float* rp = base + i * LROW + w0;
                float4 a = *(const float4*)(rp);
                float4 c = *(const float4*)(rp + 4);
                float f[8] = {a.x, a.y, a.z, a.w, c.x, c.y, c.z, c.w};
#pragma unroll
                for (int j = 0; j < KS; ++j)
#pragma unroll
                    for (int p = 0; p < 4; ++p)
                        s[p][i * KS + j] = fmaf(f[p + j], ctr[p], s[p][i * KS + j]);
            }
            if (t == 31) {
                // softmax over 25 taps per pixel (padded taps are exactly 0
                // pre-softmax and keep their denominator share -> matches ref)
#pragma unroll
                for (int p = 0; p < 4; ++p) {
                    float m = -INFINITY;
#pragma unroll
                    for (int k = 0; k < K2; ++k) {
                        float v = s[p][k] * kw[k];
                        s[p][k] = v;
                        m = fmaxf(m, v);
                    }
                    float sum = 0.0f;
#pragma unroll
                    for (int k = 0; k < K2; ++k) {
                        float e = __expf(s[p][k] - m);
                        s[p][k] = e;
                        sum += e;
                    }
                    const float inv = 1.0f / sum;
#pragma unroll
                    for (int k = 0; k < K2; ++k) s[p][k] *= inv;
                }
            }
        } else {
            float acc[4] = {0.f, 0.f, 0.f, 0.f};
#pragma unroll
            for (int i = 0; i < KS; ++i) {
                const float* rp = base + i * LROW + w0;
                float4 a = *(const float4*)(rp);
                float4 c = *(const float4*)(rp + 4);
                float f[8] = {a.x, a.y, a.z, a.w, c.x, c.y, c.z, c.w};
#pragma unroll
                for (int j = 0; j < KS; ++j)
#pragma unroll
                    for (int p = 0; p < 4; ++p)
                        acc[p] = fmaf(f[p + j], s[p][i * KS + j], acc[p]);
            }
            *(float4*)(ob + (t - 32) * PLANE) = make_float4(acc[0], acc[1], acc[2], acc[3]);
        }
    };

    __syncthreads();   // zero-init + kw visible

    // prologue: ch(0)=32 straight into buf0; ch(1),ch(2) into reg sets
    float4 rA0, rA1, rA2, rB0, rB1, rB2;
    {
        float4 p0, p1, p2;
        loadset(32, p0, p1, p2);
        writeset(buf0, p0, p1, p2);
    }
    loadset(33, rA0, rA1, rA2);
    loadset(34, rB0, rB1, rB2);
    __syncthreads();

#pragma unroll 1
    for (int tt = 0; tt < 64; tt += 2) {
        compute(tt, buf0);
        writeset(buf1, rA0, rA1, rA2);               // ch tt+1 (issued 2 stages ago)
        if (tt + 3 < 64) loadset(CH(tt + 3), rA0, rA1, rA2);
        __syncthreads();

        compute(tt + 1, buf1);
        if (tt + 2 < 64) {
            writeset(buf0, rB0, rB1, rB2);           // ch tt+2
            if (tt + 4 < 64) loadset(CH(tt + 4), rB0, rB1, rB2);
            __syncthreads();
        }
    }
}

extern "C" void kernel_launch(void* const* d_in, const int* in_sizes, int n_in,
                              void* d_out, int out_size, void* d_ws, size_t ws_size,
                              hipStream_t stream) {
    const float* x    = (const float*)d_in[0];
    const float* kern = (const float*)d_in[1];
    float*       out  = (float*)d_out;

    dim3 grid(HH / 2, BB, 1);
    dim3 block(NTHR, 1, 1);
    hipLaunchKernelGGL(local_attn_kernel, grid, block, 0, stream, x, kern, out);
}

// Round 6
// 126.084 us; speedup vs baseline: 1.0891x; 1.0891x over previous
//
#include <hip/hip_runtime.h>
#include <math.h>

#define KS    5
#define K2    25
#define DYN   32
#define BB    4
#define HH    256
#define WW    256
#define PLANE (HH * WW)
#define LROW  264                 // floats per tile row: 4 pad | 256 data | 4 pad
#define TROWS 6                   // input rows per tile (2 out rows + 4 halo)
#define NCH   4                   // channels staged per stage
#define CHBLK (TROWS * LROW + 8)  // +8 floats: de-phase lane halves by 16 banks
#define NTHR  256

typedef const __attribute__((address_space(1))) void* gas_t;
typedef __attribute__((address_space(3))) void*       las_t;

// Block = 2 output rows x 256 cols, 4 waves. Lane l: cg=l>>5 (channel half),
// pixel-group tx = (wave&1)*32 + (l&31), 4 px/thread. 16 stages x 4 channels
// (score ch 32..63 then output ch 0..31), double-buffered LDS filled by
// global_load_lds DMA (no ds_write, no VGPR roundtrip). Halo/pad rows stay
// zero from init => zero-padding implicit, zero masking instructions.
__global__ __launch_bounds__(NTHR, 2)
void local_attn_kernel(const float* __restrict__ x,
                       const float* __restrict__ kern,
                       float* __restrict__ out)
{
    __shared__ __align__(16) float lds[2][NCH][CHBLK];
    __shared__ float kw[K2];

    const int tid = threadIdx.x;
    for (int i = tid; i < 2 * NCH * CHBLK; i += NTHR) ((float*)lds)[i] = 0.0f;
    if (tid < K2) kw[tid] = kern[tid] * (1.0f / KS);

    const int lane = tid & 63;
    const int wv   = tid >> 6;       // wave 0..3 (uniform per wave)
    const int ty   = wv >> 1;        // output row within block
    const int cg   = lane >> 5;      // channel half (0/1)
    const int tx   = ((wv & 1) << 5) | (lane & 31);   // pixel-group 0..63
    const int w0   = tx << 2;

    // XCD swizzle: XCD k owns a contiguous 32-row band -> halo rows L2-shared
    const int bx     = blockIdx.x;                     // 0..127
    const int hgroup = ((bx & 7) << 4) | (bx >> 3);
    const int h0     = hgroup * 2;
    const int b      = blockIdx.y;
    const int h      = h0 + ty;

    const float* xb = x + (size_t)b * 64 * PLANE;

    // staging rows: wave wv stages channel (chbase + wv), rows j=0..5
    bool rok[TROWS]; int roff[TROWS];
#pragma unroll
    for (int j = 0; j < TROWS; ++j) {
        const int r = h0 - 2 + j;
        rok[j]  = (unsigned)r < (unsigned)HH;
        roff[j] = r * WW;
    }

    auto stagein = [&](int bufi, int chbase) {
        const float* cp = xb + (size_t)(chbase + wv) * PLANE;
#pragma unroll
        for (int j = 0; j < TROWS; ++j) {
            if (rok[j]) {   // wave-uniform branch
                __builtin_amdgcn_global_load_lds(
                    (gas_t)(const void*)(cp + roff[j] + 4 * lane),
                    (las_t)(void*)(&lds[bufi][wv][j * LROW + 4]),
                    16, 0, 0);
            }
        }
    };

    float s[4][K2];
#pragma unroll
    for (int p = 0; p < 4; ++p)
#pragma unroll
        for (int k = 0; k < K2; ++k) s[p][k] = 0.0f;

    // f[q] <-> LDS idx w0+q <-> image col w0+q-4; tap (p,j) -> f[p+j+2]
    auto compute_score = [&](int bufi) {
#pragma unroll
        for (int dch = 0; dch < 2; ++dch) {
            const int cl = cg * 2 + dch;
            const float* cb = &lds[bufi][cl][0];
            float ctr[4];
            {   // center row first (i = 2)
                const float* rp = cb + (ty + 2) * LROW + w0;
                float4 a = *(const float4*)(rp);
                float4 m = *(const float4*)(rp + 4);
                float4 c = *(const float4*)(rp + 8);
                float f[12] = {a.x,a.y,a.z,a.w, m.x,m.y,m.z,m.w, c.x,c.y,c.z,c.w};
                ctr[0]=f[4]; ctr[1]=f[5]; ctr[2]=f[6]; ctr[3]=f[7];
#pragma unroll
                for (int j = 0; j < KS; ++j)
#pragma unroll
                    for (int p = 0; p < 4; ++p)
                        s[p][2*KS+j] = fmaf(f[p+j+2], ctr[p], s[p][2*KS+j]);
            }
#pragma unroll
            for (int i = 0; i < KS; ++i) {
                if (i == 2) continue;
                const float* rp = cb + (ty + i) * LROW + w0;
                float4 a = *(const float4*)(rp);
                float4 m = *(const float4*)(rp + 4);
                float4 c = *(const float4*)(rp + 8);
                float f[12] = {a.x,a.y,a.z,a.w, m.x,m.y,m.z,m.w, c.x,c.y,c.z,c.w};
#pragma unroll
                for (int j = 0; j < KS; ++j)
#pragma unroll
                    for (int p = 0; p < 4; ++p)
                        s[p][i*KS+j] = fmaf(f[p+j+2], ctr[p], s[p][i*KS+j]);
            }
        }
    };

    auto compute_out = [&](int bufi, int chbase) {
#pragma unroll
        for (int dch = 0; dch < 2; ++dch) {
            const int cl = cg * 2 + dch;
            const float* cb = &lds[bufi][cl][0];
            float acc[4] = {0.f, 0.f, 0.f, 0.f};
#pragma unroll
            for (int i = 0; i < KS; ++i) {
                const float* rp = cb + (ty + i) * LROW + w0;
                float4 a = *(const float4*)(rp);
                float4 m = *(const float4*)(rp + 4);
                float4 c = *(const float4*)(rp + 8);
                float f[12] = {a.x,a.y,a.z,a.w, m.x,m.y,m.z,m.w, c.x,c.y,c.z,c.w};
#pragma unroll
                for (int j = 0; j < KS; ++j)
#pragma unroll
                    for (int p = 0; p < 4; ++p)
                        acc[p] = fmaf(f[p+j+2], s[p][i*KS+j], acc[p]);
            }
            *(float4*)(out + ((size_t)b * DYN + chbase + cl) * PLANE + h * WW + w0)
                = make_float4(acc[0], acc[1], acc[2], acc[3]);
        }
    };

    __syncthreads();           // zero-init + kw visible
    stagein(0, 32);            // stage 0: channels 32..35 -> buf0
    __syncthreads();           // vmcnt(0) drain before barrier completes DMA

#pragma unroll 1
    for (int t = 0; t < 16; ++t) {
        if (t + 1 < 16)
            stagein((t + 1) & 1, (t + 1 < 8) ? 32 + 4 * (t + 1) : 4 * (t + 1 - 8));
        if (t < 8) {
            compute_score(t & 1);
            if (t == 7) {
                // combine the two channel halves, then softmax over 25 taps.
                // zero-padded taps score exactly 0 and keep their softmax
                // denominator share (matches reference).
#pragma unroll
                for (int p = 0; p < 4; ++p)
#pragma unroll
                    for (int k = 0; k < K2; ++k)
                        s[p][k] += __shfl_xor(s[p][k], 32, 64);
#pragma unroll
                for (int p = 0; p < 4; ++p) {
                    float mx = -INFINITY;
#pragma unroll
                    for (int k = 0; k < K2; ++k) {
                        float v = s[p][k] * kw[k];
                        s[p][k] = v;
                        mx = fmaxf(mx, v);
                    }
                    float sum = 0.0f;
#pragma unroll
                    for (int k = 0; k < K2; ++k) {
                        float e = __expf(s[p][k] - mx);
                        s[p][k] = e;
                        sum += e;
                    }
                    const float inv = 1.0f / sum;
#pragma unroll
                    for (int k = 0; k < K2; ++k) s[p][k] *= inv;
                }
            }
        } else {
            compute_out(t & 1, 4 * (t - 8));
        }
        __syncthreads();
    }
}

extern "C" void kernel_launch(void* const* d_in, const int* in_sizes, int n_in,
                              void* d_out, int out_size, void* d_ws, size_t ws_size,
                              hipStream_t stream) {
    const float* x    = (const float*)d_in[0];
    const float* kern = (const float*)d_in[1];
    float*       out  = (float*)d_out;

    dim3 grid(HH / 2, BB, 1);
    dim3 block(NTHR, 1, 1);
    hipLaunchKernelGGL(local_attn_kernel, grid, block, 0, stream, x, kern, out);
}

// Round 8
// 113.663 us; speedup vs baseline: 1.2081x; 1.1093x over previous
//
#include <hip/hip_runtime.h>
#include <math.h>

#define KS    5
#define K2    25
#define BB    4
#define HH    256
#define WW    256
#define PLANE (HH * WW)
#define LROWD 264     // dwords per tile row: [2 halo][256 px][2 halo][4 pad]
#define PTILE 1864    // 7 rows * 264 + 16 pad; %32==8 -> cg stride (2*PTILE) == 16 banks
#define NTHR  256

typedef __attribute__((ext_vector_type(2))) _Float16 half2_t;

static __device__ __forceinline__ half2_t u2h(unsigned u) { return __builtin_bit_cast(half2_t, u); }

static __device__ __forceinline__ unsigned pkrtz(float a, float b) {
    auto h = __builtin_amdgcn_cvt_pkrtz(a, b);   // __fp16 ext_vector(2), 4 bytes
    return __builtin_bit_cast(unsigned, h);
}

static __device__ __forceinline__ float dot2(half2_t a, half2_t b, float c) {
#if __has_builtin(__builtin_amdgcn_fdot2)
    return __builtin_amdgcn_fdot2(a, b, c, false);
#else
    return (float)a.x * (float)b.x + ((float)a.y * (float)b.y + c);
#endif
}

// Block = 2 output rows x 256 cols, 4 waves, 4 px/thread, channel-pair f16 tile.
// 8 stages x 8 channels (score: 32..63, output: 0..31), double-buffered LDS.
// Tile dword = half2(ch c, ch c+1) per pixel -> 2 ds_read_b128 per window row,
// v_dot2 = 2 MACs/instr for scores. Zeroed halo/OOB rows => implicit padding.
__global__ __launch_bounds__(NTHR, 2)
void local_attn_kernel(const float* __restrict__ x,
                       const float* __restrict__ kern,
                       float* __restrict__ out)
{
    __shared__ unsigned ldsu[2 * 4 * PTILE];
    __shared__ float kw[K2];

    const int tid = threadIdx.x;
    for (int i = tid; i < 2 * 4 * PTILE; i += NTHR) ldsu[i] = 0u;
    if (tid < K2) kw[tid] = kern[tid] * (1.0f / KS);

    const int lane = tid & 63;
    const int wv   = tid >> 6;
    const int ty   = wv >> 1;                       // output row in block
    const int cg   = lane >> 5;                     // pair-half (0/1)
    const int tx   = ((wv & 1) << 5) | (lane & 31); // pixel-group 0..63
    const int w0   = tx << 2;

    // XCD swizzle: each XCD owns a contiguous 32-row band (halo L2-shared)
    const int bx     = blockIdx.x;
    const int hgroup = ((bx & 7) << 4) | (bx >> 3);
    const int h0     = hgroup * 2;
    const int h      = h0 + ty;
    const int b      = blockIdx.y;

    const float* xb = x + (size_t)b * 64 * PLANE;

    // 6 staging tasks/thread: task i -> (pair, tile row, 4-px segment)
    int gofs[6], lofs[6], pofs[6];
#pragma unroll
    for (int i = 0; i < 6; ++i) {
        const int rp   = (tid >> 6) + 4 * i;        // 0..23 (wave-uniform)
        const int row  = rp % 6;
        const int pair = rp / 6;
        const int r    = h0 - 2 + row;
        const bool v   = (unsigned)r < (unsigned)HH;
        gofs[i] = min(max(r, 0), HH - 1) * WW + (tid & 63) * 4;
        pofs[i] = pair * 2 * PLANE;
        lofs[i] = pair * PTILE + (v ? row : 6) * LROWD + 2 + (tid & 63) * 4;
    }

    float4 pa[6], pb[6];
    auto prefetch = [&](int st) {
        const float* xc = xb + (size_t)((st < 4) ? 32 + st * 8 : (st - 4) * 8) * PLANE;
#pragma unroll
        for (int i = 0; i < 6; ++i) {
            pa[i] = *(const float4*)(xc + pofs[i] + gofs[i]);
            pb[i] = *(const float4*)(xc + pofs[i] + PLANE + gofs[i]);
        }
    };
    auto cvtwrite = [&](int bufi) {
        unsigned* lb = ldsu + bufi * 4 * PTILE;
#pragma unroll
        for (int i = 0; i < 6; ++i) {
            const unsigned d0 = pkrtz(pa[i].x, pb[i].x);
            const unsigned d1 = pkrtz(pa[i].y, pb[i].y);
            const unsigned d2 = pkrtz(pa[i].z, pb[i].z);
            const unsigned d3 = pkrtz(pa[i].w, pb[i].w);
            *(uint2*)(lb + lofs[i])     = make_uint2(d0, d1);
            *(uint2*)(lb + lofs[i] + 2) = make_uint2(d2, d3);
        }
    };

    float s[4][K2];
#pragma unroll
    for (int p = 0; p < 4; ++p)
#pragma unroll
        for (int k = 0; k < K2; ++k) s[p][k] = 0.0f;

    __syncthreads();          // zero-init + kw visible
    prefetch(0);
    cvtwrite(0);
    __syncthreads();

#pragma unroll 1
    for (int t = 0; t < 8; ++t) {
        if (t + 1 < 8) prefetch(t + 1);
        const unsigned* buf = ldsu + (t & 1) * 4 * PTILE;

        if (t < 4) {
            // ---- score: 2 channel-pairs per lane-half, dot2 accumulate ----
#pragma unroll
            for (int dp = 0; dp < 2; ++dp) {
                const unsigned* tb = buf + (cg * 2 + dp) * PTILE;
                half2_t ctr[4];
                {   // center row (i=2) first: f[q] = pair at px w0-2+q
                    const unsigned* rp = tb + (ty + 2) * LROWD + w0;
                    const uint4 r0 = *(const uint4*)(rp);
                    const uint4 r1 = *(const uint4*)(rp + 4);
                    half2_t f[8] = {u2h(r0.x), u2h(r0.y), u2h(r0.z), u2h(r0.w),
                                    u2h(r1.x), u2h(r1.y), u2h(r1.z), u2h(r1.w)};
#pragma unroll
                    for (int p = 0; p < 4; ++p) ctr[p] = f[p + 2];
#pragma unroll
                    for (int j = 0; j < KS; ++j)
#pragma unroll
                        for (int p = 0; p < 4; ++p)
                            s[p][2 * KS + j] = dot2(f[p + j], ctr[p], s[p][2 * KS + j]);
                }
#pragma unroll
                for (int i = 0; i < KS; ++i) {
                    if (i == 2) continue;
                    const unsigned* rp = tb + (ty + i) * LROWD + w0;
                    const uint4 r0 = *(const uint4*)(rp);
                    const uint4 r1 = *(const uint4*)(rp + 4);
                    half2_t f[8] = {u2h(r0.x), u2h(r0.y), u2h(r0.z), u2h(r0.w),
                                    u2h(r1.x), u2h(r1.y), u2h(r1.z), u2h(r1.w)};
#pragma unroll
                    for (int j = 0; j < KS; ++j)
#pragma unroll
                        for (int p = 0; p < 4; ++p)
                            s[p][i * KS + j] = dot2(f[p + j], ctr[p], s[p][i * KS + j]);
                }
            }
            if (t == 3) {
                // combine pair-halves, then softmax over 25 taps.
                // zero-padded taps score exactly 0 and keep their denominator
                // share (matches reference).
#pragma unroll
                for (int p = 0; p < 4; ++p)
#pragma unroll
                    for (int k = 0; k < K2; ++k)
                        s[p][k] += __shfl_xor(s[p][k], 32, 64);
#pragma unroll
                for (int p = 0; p < 4; ++p) {
                    float mx = -INFINITY;
#pragma unroll
                    for (int k = 0; k < K2; ++k) {
                        float v = s[p][k] * kw[k];
                        s[p][k] = v;
                        mx = fmaxf(mx, v);
                    }
                    float sum = 0.0f;
#pragma unroll
                    for (int k = 0; k < K2; ++k) {
                        float e = __expf(s[p][k] - mx);
                        s[p][k] = e;
                        sum += e;
                    }
                    const float inv = 1.0f / sum;
#pragma unroll
                    for (int k = 0; k < K2; ++k) s[p][k] *= inv;
                }
            }
        } else {
            // ---- output: weighted sum; fp32 accumulate via mixed FMA ----
            const int chb = (t - 4) * 8;
#pragma unroll
            for (int dp = 0; dp < 2; ++dp) {
                const unsigned* tb = buf + (cg * 2 + dp) * PTILE;
                float alo[4] = {0.f, 0.f, 0.f, 0.f};
                float ahi[4] = {0.f, 0.f, 0.f, 0.f};
#pragma unroll
                for (int i = 0; i < KS; ++i) {
                    const unsigned* rp = tb + (ty + i) * LROWD + w0;
                    const uint4 r0 = *(const uint4*)(rp);
                    const uint4 r1 = *(const uint4*)(rp + 4);
                    half2_t f[8] = {u2h(r0.x), u2h(r0.y), u2h(r0.z), u2h(r0.w),
                                    u2h(r1.x), u2h(r1.y), u2h(r1.z), u2h(r1.w)};
#pragma unroll
                    for (int j = 0; j < KS; ++j)
#pragma unroll
                        for (int p = 0; p < 4; ++p) {
                            const half2_t v = f[p + j];
                            const float  wgt = s[p][i * KS + j];
                            alo[p] = fmaf((float)v.x, wgt, alo[p]);
                            ahi[p] = fmaf((float)v.y, wgt, ahi[p]);
                        }
                }
                const int c0 = chb + (cg * 2 + dp) * 2;
                float* op = out + ((size_t)b * 32 + c0) * PLANE + h * WW + w0;
                *(float4*)op           = make_float4(alo[0], alo[1], alo[2], alo[3]);
                *(float4*)(op + PLANE) = make_float4(ahi[0], ahi[1], ahi[2], ahi[3]);
            }
        }

        if (t + 1 < 8) {
            cvtwrite((t + 1) & 1);
            __syncthreads();
        }
    }
}

extern "C" void kernel_launch(void* const* d_in, const int* in_sizes, int n_in,
                              void* d_out, int out_size, void* d_ws, size_t ws_size,
                              hipStream_t stream) {
    const float* x    = (const float*)d_in[0];
    const float* kern = (const float*)d_in[1];
    float*       out  = (float*)d_out;

    dim3 grid(HH / 2, BB, 1);
    dim3 block(NTHR, 1, 1);
    hipLaunchKernelGGL(local_attn_kernel, grid, block, 0, stream, x, kern, out);
}